// Round 1
// baseline (834.301 us; speedup 1.0000x reference)
//
#include <hip/hip_runtime.h>
#include <stdint.h>

typedef __bf16 bf16;
typedef __attribute__((ext_vector_type(8))) bf16 bf16x8;
typedef __attribute__((ext_vector_type(4))) bf16 bf16x4;
typedef __attribute__((ext_vector_type(4))) float f32x4;

#define T_DIM 512
#define H_DIM 4096
#define F_DIM 14336

// ---------------------------------------------------------------------------
// x (f32) -> bf16
__global__ void cvt_x_kernel(const float* __restrict__ x, bf16* __restrict__ xb) {
    int i = (blockIdx.x * 256 + threadIdx.x) * 4;
    float4 v = *(const float4*)(x + i);
    bf16x4 o = {(bf16)v.x, (bf16)v.y, (bf16)v.z, (bf16)v.w};
    *(bf16x4*)(xb + i) = o;
}

// inter = silu(gate) * up, in-place into gate buffer
__global__ void silu_mul_kernel(bf16* __restrict__ g, const bf16* __restrict__ u) {
    int i = (blockIdx.x * 256 + threadIdx.x) * 8;
    bf16x8 gv = *(const bf16x8*)(g + i);
    bf16x8 uv = *(const bf16x8*)(u + i);
    bf16x8 ov;
#pragma unroll
    for (int j = 0; j < 8; j++) {
        float gf = (float)gv[j];
        float s  = gf / (1.0f + __expf(-gf));
        ov[j] = (bf16)(s * (float)uv[j]);
    }
    *(bf16x8*)(g + i) = ov;
}

// ---------------------------------------------------------------------------
// GEMM: Out[M,N] = A[M,K] @ dequant(Wq[N,K])^T
//   dequant: W[n,k] = ((float)Wq[n,k] - zero[n>>6, k]) * scale[n>>6, k]
// 128x128 tile, BK=32, 256 threads (4 waves, 2x2 of 64x64), mfma 16x16x32 bf16.
template<int KD, bool OUT_F32>
__global__ __launch_bounds__(256, 2)
void gemm_hqq(const bf16* __restrict__ A, const int* __restrict__ Wq,
              const float* __restrict__ Sc, const float* __restrict__ Zr,
              void* __restrict__ Out) {
    __shared__ __align__(16) bf16 As[128][32];
    __shared__ __align__(16) bf16 Bs[128][32];

    const int tid  = threadIdx.x;
    const int lane = tid & 63;
    const int wid  = tid >> 6;
    const int wm   = wid >> 1;      // 0..1
    const int wn   = wid & 1;       // 0..1
    const int lr   = lane & 15;
    const int lk   = (lane >> 4) * 8;
    const int m0   = blockIdx.y * 128;
    const int n0   = blockIdx.x * 128;
    const int Nld  = gridDim.x * 128;

    // A staging: 2 passes of 16B/thread. row = tid>>2 (+p*64), col = (tid&3)*8
    const int ar = tid >> 2;
    const int ac = (tid & 3) * 8;
    // B staging: 4 passes of int4 + dequant. row = tid>>3 (+j*32), col = (tid&7)*4
    const int br = tid >> 3;
    const int bc = (tid & 7) * 4;

    f32x4 acc[4][4];
    const f32x4 zf = {0.f, 0.f, 0.f, 0.f};
#pragma unroll
    for (int i = 0; i < 4; i++)
#pragma unroll
        for (int j = 0; j < 4; j++) acc[i][j] = zf;

    bf16x8 areg[2];
    int4   qreg[4];
    float4 sreg[4], zreg[4];

#define LOAD_TILES(K0)                                                          \
    {                                                                           \
        _Pragma("unroll")                                                       \
        for (int p = 0; p < 2; p++)                                             \
            areg[p] = *(const bf16x8*)(A + (size_t)(m0 + ar + p * 64) * KD + (K0) + ac); \
        _Pragma("unroll")                                                       \
        for (int j = 0; j < 4; j++) {                                           \
            int gr = n0 + br + j * 32;                                          \
            qreg[j] = *(const int4*)(Wq + (size_t)gr * KD + (K0) + bc);         \
            int gg = gr >> 6;                                                   \
            sreg[j] = *(const float4*)(Sc + (size_t)gg * KD + (K0) + bc);       \
            zreg[j] = *(const float4*)(Zr + (size_t)gg * KD + (K0) + bc);       \
        }                                                                       \
    }

    LOAD_TILES(0);

    for (int k0 = 0; k0 < KD; k0 += 32) {
        __syncthreads();   // previous compute done reading LDS
        // write staged tiles to LDS (dequant B here)
#pragma unroll
        for (int p = 0; p < 2; p++)
            *(bf16x8*)&As[ar + p * 64][ac] = areg[p];
#pragma unroll
        for (int j = 0; j < 4; j++) {
            bf16x4 hv;
            hv[0] = (bf16)(((float)qreg[j].x - zreg[j].x) * sreg[j].x);
            hv[1] = (bf16)(((float)qreg[j].y - zreg[j].y) * sreg[j].y);
            hv[2] = (bf16)(((float)qreg[j].z - zreg[j].z) * sreg[j].z);
            hv[3] = (bf16)(((float)qreg[j].w - zreg[j].w) * sreg[j].w);
            *(bf16x4*)&Bs[br + j * 32][bc] = hv;
        }
        __syncthreads();

        if (k0 + 32 < KD) LOAD_TILES(k0 + 32);  // prefetch next tile into regs

        bf16x8 af[4], bfr[4];
#pragma unroll
        for (int mi = 0; mi < 4; mi++)
            af[mi] = *(const bf16x8*)&As[wm * 64 + mi * 16 + lr][lk];
#pragma unroll
        for (int ni = 0; ni < 4; ni++)
            bfr[ni] = *(const bf16x8*)&Bs[wn * 64 + ni * 16 + lr][lk];
#pragma unroll
        for (int mi = 0; mi < 4; mi++)
#pragma unroll
            for (int ni = 0; ni < 4; ni++)
                acc[mi][ni] = __builtin_amdgcn_mfma_f32_16x16x32_bf16(
                    af[mi], bfr[ni], acc[mi][ni], 0, 0, 0);
    }
#undef LOAD_TILES

    // Epilogue: C/D layout row = (lane>>4)*4 + r, col = lane&15
    const int orow = (lane >> 4) * 4;
    if constexpr (OUT_F32) {
        float* o = (float*)Out;
#pragma unroll
        for (int mi = 0; mi < 4; mi++)
#pragma unroll
            for (int ni = 0; ni < 4; ni++) {
                f32x4 v = acc[mi][ni];
                int r0 = m0 + wm * 64 + mi * 16 + orow;
                int c  = n0 + wn * 64 + ni * 16 + lr;
#pragma unroll
                for (int r = 0; r < 4; r++)
                    o[(size_t)(r0 + r) * Nld + c] = v[r];
            }
    } else {
        bf16* o = (bf16*)Out;
#pragma unroll
        for (int mi = 0; mi < 4; mi++)
#pragma unroll
            for (int ni = 0; ni < 4; ni++) {
                f32x4 v = acc[mi][ni];
                int r0 = m0 + wm * 64 + mi * 16 + orow;
                int c  = n0 + wn * 64 + ni * 16 + lr;
#pragma unroll
                for (int r = 0; r < 4; r++)
                    o[(size_t)(r0 + r) * Nld + c] = (bf16)v[r];
            }
    }
}

// ---------------------------------------------------------------------------
extern "C" void kernel_launch(void* const* d_in, const int* in_sizes, int n_in,
                              void* d_out, int out_size, void* d_ws, size_t ws_size,
                              hipStream_t stream) {
    const float* x   = (const float*)d_in[0];
    const int*   w1q = (const int*)d_in[1];
    const float* w1s = (const float*)d_in[2];
    const float* w1z = (const float*)d_in[3];
    const int*   w2q = (const int*)d_in[4];
    const float* w2s = (const float*)d_in[5];
    const float* w2z = (const float*)d_in[6];
    const int*   w3q = (const int*)d_in[7];
    const float* w3s = (const float*)d_in[8];
    const float* w3z = (const float*)d_in[9];

    bf16* xb   = (bf16*)d_ws;                      // [512][4096]  bf16 (4 MB)
    bf16* gate = xb + (size_t)T_DIM * H_DIM;       // [512][14336] bf16 (14 MB)
    bf16* up   = gate + (size_t)T_DIM * F_DIM;     // [512][14336] bf16 (14 MB)

    // x -> bf16  (512*4096 / (256*4) = 2048 blocks)
    cvt_x_kernel<<<dim3(2048), dim3(256), 0, stream>>>(x, xb);

    // gate = x @ W1^T ; up = x @ W3^T   (grid 112 x 4)
    gemm_hqq<H_DIM, false><<<dim3(F_DIM / 128, T_DIM / 128), dim3(256), 0, stream>>>(
        xb, w1q, w1s, w1z, gate);
    gemm_hqq<H_DIM, false><<<dim3(F_DIM / 128, T_DIM / 128), dim3(256), 0, stream>>>(
        xb, w3q, w3s, w3z, up);

    // inter = silu(gate)*up, in-place into gate  (512*14336 / (256*8) = 3584 blocks)
    silu_mul_kernel<<<dim3(3584), dim3(256), 0, stream>>>(gate, up);

    // out = inter @ W2^T  (grid 32 x 4, f32 output)
    gemm_hqq<F_DIM, true><<<dim3(H_DIM / 128, T_DIM / 128), dim3(256), 0, stream>>>(
        gate, w2q, w2s, w2z, (float*)d_out);
}

// Round 2
// 704.283 us; speedup vs baseline: 1.1846x; 1.1846x over previous
//
#include <hip/hip_runtime.h>
#include <stdint.h>

typedef __bf16 bf16;
typedef __attribute__((ext_vector_type(2))) bf16 bf16x2;
typedef __attribute__((ext_vector_type(8))) bf16 bf16x8;
typedef __attribute__((ext_vector_type(4))) bf16 bf16x4;
typedef __attribute__((ext_vector_type(4))) float f32x4;

#define T_DIM 512
#define H_DIM 4096
#define F_DIM 14336
#define LDP 40   // padded LDS row (bf16 elems): 80 B -> 4-way max bank conflict

// ---------------------------------------------------------------------------
// x (f32) -> bf16
__global__ void cvt_x_kernel(const float* __restrict__ x, bf16* __restrict__ xb) {
    int i = (blockIdx.x * 256 + threadIdx.x) * 4;
    float4 v = *(const float4*)(x + i);
    bf16x4 o = {(bf16)v.x, (bf16)v.y, (bf16)v.z, (bf16)v.w};
    *(bf16x4*)(xb + i) = o;
}

// ---------------------------------------------------------------------------
// Phase 1: inter = silu(x @ W1^T) * (x @ W3^T), fused.
// Full-M blocks: grid.x = F/32 = 448, block = 512 threads (8 waves).
// Wave w computes rows [w*64, w*64+64) x cols [n0, n0+32) of BOTH gemms.
__global__ __launch_bounds__(512, 2)
void gemm_gateup(const bf16* __restrict__ A,
                 const int* __restrict__ Wq1, const float* __restrict__ Sc1,
                 const float* __restrict__ Zr1,
                 const int* __restrict__ Wq3, const float* __restrict__ Sc3,
                 const float* __restrict__ Zr3,
                 bf16* __restrict__ inter) {
    constexpr int K = H_DIM;
    __shared__ __align__(16) bf16 As[T_DIM][LDP];
    __shared__ __align__(16) bf16 Bs1[32][LDP];
    __shared__ __align__(16) bf16 Bs3[32][LDP];

    const int tid  = threadIdx.x;
    const int lane = tid & 63;
    const int w    = tid >> 6;          // 0..7
    const int lr   = lane & 15;
    const int lk   = (lane >> 4) * 8;
    const int n0   = blockIdx.x * 32;
    const int g    = n0 >> 6;           // HQQ group row (constant: 32-row tile never crosses a 64 boundary)

    // A staging: 4 passes, 16B/thread. row = tid>>2 (+p*128), col = (tid&3)*8
    const int ar = tid >> 2;
    const int ac = (tid & 3) * 8;
    // B staging: 2 int / thread per weight. row = tid>>4, col = (tid&15)*2
    const int br = tid >> 4;
    const int bc = (tid & 15) * 2;

    f32x4 acc1[4][2], acc3[4][2];
    const f32x4 zf = {0.f, 0.f, 0.f, 0.f};
#pragma unroll
    for (int i = 0; i < 4; i++)
#pragma unroll
        for (int j = 0; j < 2; j++) { acc1[i][j] = zf; acc3[i][j] = zf; }

    bf16x8 areg[4];
    int2 q1, q3; float2 s1, z1, s3, z3;

#define LOAD_TILES(K0)                                                           \
    {                                                                            \
        _Pragma("unroll")                                                        \
        for (int p = 0; p < 4; p++)                                              \
            areg[p] = *(const bf16x8*)(A + (size_t)(ar + p * 128) * K + (K0) + ac); \
        q1 = *(const int2*)(Wq1 + (size_t)(n0 + br) * K + (K0) + bc);            \
        q3 = *(const int2*)(Wq3 + (size_t)(n0 + br) * K + (K0) + bc);            \
        s1 = *(const float2*)(Sc1 + (size_t)g * K + (K0) + bc);                  \
        z1 = *(const float2*)(Zr1 + (size_t)g * K + (K0) + bc);                  \
        s3 = *(const float2*)(Sc3 + (size_t)g * K + (K0) + bc);                  \
        z3 = *(const float2*)(Zr3 + (size_t)g * K + (K0) + bc);                  \
    }

    LOAD_TILES(0);

    for (int k0 = 0; k0 < K; k0 += 32) {
        __syncthreads();
#pragma unroll
        for (int p = 0; p < 4; p++)
            *(bf16x8*)&As[ar + p * 128][ac] = areg[p];
        {
            bf16x2 v1, v3;
            v1[0] = (bf16)(((float)q1.x - z1.x) * s1.x);
            v1[1] = (bf16)(((float)q1.y - z1.y) * s1.y);
            v3[0] = (bf16)(((float)q3.x - z3.x) * s3.x);
            v3[1] = (bf16)(((float)q3.y - z3.y) * s3.y);
            *(bf16x2*)&Bs1[br][bc] = v1;
            *(bf16x2*)&Bs3[br][bc] = v3;
        }
        __syncthreads();

        if (k0 + 32 < K) LOAD_TILES(k0 + 32);

        bf16x8 af[4], b1[2], b3[2];
#pragma unroll
        for (int mi = 0; mi < 4; mi++)
            af[mi] = *(const bf16x8*)&As[w * 64 + mi * 16 + lr][lk];
#pragma unroll
        for (int ni = 0; ni < 2; ni++) {
            b1[ni] = *(const bf16x8*)&Bs1[ni * 16 + lr][lk];
            b3[ni] = *(const bf16x8*)&Bs3[ni * 16 + lr][lk];
        }
#pragma unroll
        for (int mi = 0; mi < 4; mi++)
#pragma unroll
            for (int ni = 0; ni < 2; ni++) {
                acc1[mi][ni] = __builtin_amdgcn_mfma_f32_16x16x32_bf16(af[mi], b1[ni], acc1[mi][ni], 0, 0, 0);
                acc3[mi][ni] = __builtin_amdgcn_mfma_f32_16x16x32_bf16(af[mi], b3[ni], acc3[mi][ni], 0, 0, 0);
            }
    }
#undef LOAD_TILES

    // Epilogue: inter = silu(gate) * up.  C/D: row = (lane>>4)*4 + r, col = lane&15
    const int orow = (lane >> 4) * 4;
#pragma unroll
    for (int mi = 0; mi < 4; mi++)
#pragma unroll
        for (int ni = 0; ni < 2; ni++) {
#pragma unroll
            for (int r = 0; r < 4; r++) {
                int m = w * 64 + mi * 16 + orow + r;
                int c = n0 + ni * 16 + lr;
                float gf = acc1[mi][ni][r];
                float uf = acc3[mi][ni][r];
                float sv = gf / (1.0f + __expf(-gf));
                inter[(size_t)m * F_DIM + c] = (bf16)(sv * uf);
            }
        }
}

// ---------------------------------------------------------------------------
// Phase 2: partial[s] = inter[:, ks:ke] @ W2[:, ks:ke]^T  (f32 partials)
// grid = (H/32, SPLITK), block = 512 threads.
template<int SPLITK>
__global__ __launch_bounds__(512, 2)
void gemm_down(const bf16* __restrict__ A, const int* __restrict__ Wq,
               const float* __restrict__ Sc, const float* __restrict__ Zr,
               float* __restrict__ partials) {
    constexpr int K = F_DIM;
    constexpr int KC = K / SPLITK;
    __shared__ __align__(16) bf16 As[T_DIM][LDP];
    __shared__ __align__(16) bf16 Bs[32][LDP];

    const int tid  = threadIdx.x;
    const int lane = tid & 63;
    const int w    = tid >> 6;
    const int lr   = lane & 15;
    const int lk   = (lane >> 4) * 8;
    const int n0   = blockIdx.x * 32;
    const int g    = n0 >> 6;
    const int kbeg = blockIdx.y * KC;
    const int kend = kbeg + KC;

    const int ar = tid >> 2;
    const int ac = (tid & 3) * 8;
    const int br = tid >> 4;
    const int bc = (tid & 15) * 2;

    f32x4 acc[4][2];
    const f32x4 zf = {0.f, 0.f, 0.f, 0.f};
#pragma unroll
    for (int i = 0; i < 4; i++)
#pragma unroll
        for (int j = 0; j < 2; j++) acc[i][j] = zf;

    bf16x8 areg[4];
    int2 q; float2 s, z;

#define LOAD_TILES(K0)                                                           \
    {                                                                            \
        _Pragma("unroll")                                                        \
        for (int p = 0; p < 4; p++)                                              \
            areg[p] = *(const bf16x8*)(A + (size_t)(ar + p * 128) * K + (K0) + ac); \
        q = *(const int2*)(Wq + (size_t)(n0 + br) * K + (K0) + bc);              \
        s = *(const float2*)(Sc + (size_t)g * K + (K0) + bc);                    \
        z = *(const float2*)(Zr + (size_t)g * K + (K0) + bc);                    \
    }

    LOAD_TILES(kbeg);

    for (int k0 = kbeg; k0 < kend; k0 += 32) {
        __syncthreads();
#pragma unroll
        for (int p = 0; p < 4; p++)
            *(bf16x8*)&As[ar + p * 128][ac] = areg[p];
        {
            bf16x2 v;
            v[0] = (bf16)(((float)q.x - z.x) * s.x);
            v[1] = (bf16)(((float)q.y - z.y) * s.y);
            *(bf16x2*)&Bs[br][bc] = v;
        }
        __syncthreads();

        if (k0 + 32 < kend) LOAD_TILES(k0 + 32);

        bf16x8 af[4], bf[2];
#pragma unroll
        for (int mi = 0; mi < 4; mi++)
            af[mi] = *(const bf16x8*)&As[w * 64 + mi * 16 + lr][lk];
#pragma unroll
        for (int ni = 0; ni < 2; ni++)
            bf[ni] = *(const bf16x8*)&Bs[ni * 16 + lr][lk];
#pragma unroll
        for (int mi = 0; mi < 4; mi++)
#pragma unroll
            for (int ni = 0; ni < 2; ni++)
                acc[mi][ni] = __builtin_amdgcn_mfma_f32_16x16x32_bf16(af[mi], bf[ni], acc[mi][ni], 0, 0, 0);
    }
#undef LOAD_TILES

    float* po = partials + (size_t)blockIdx.y * T_DIM * H_DIM;
    const int orow = (lane >> 4) * 4;
#pragma unroll
    for (int mi = 0; mi < 4; mi++)
#pragma unroll
        for (int ni = 0; ni < 2; ni++) {
#pragma unroll
            for (int r = 0; r < 4; r++) {
                int m = w * 64 + mi * 16 + orow + r;
                int c = n0 + ni * 16 + lr;
                po[(size_t)m * H_DIM + c] = acc[mi][ni][r];
            }
        }
}

// ---------------------------------------------------------------------------
template<int S>
__global__ void reduce_kernel(const float* __restrict__ partials, float* __restrict__ out) {
    size_t i = ((size_t)blockIdx.x * 256 + threadIdx.x) * 4;
    f32x4 a = *(const f32x4*)(partials + i);
#pragma unroll
    for (int s = 1; s < S; s++)
        a += *(const f32x4*)(partials + (size_t)s * T_DIM * H_DIM + i);
    *(f32x4*)(out + i) = a;
}

// ---------------------------------------------------------------------------
extern "C" void kernel_launch(void* const* d_in, const int* in_sizes, int n_in,
                              void* d_out, int out_size, void* d_ws, size_t ws_size,
                              hipStream_t stream) {
    const float* x   = (const float*)d_in[0];
    const int*   w1q = (const int*)d_in[1];
    const float* w1s = (const float*)d_in[2];
    const float* w1z = (const float*)d_in[3];
    const int*   w2q = (const int*)d_in[4];
    const float* w2s = (const float*)d_in[5];
    const float* w2z = (const float*)d_in[6];
    const int*   w3q = (const int*)d_in[7];
    const float* w3s = (const float*)d_in[8];
    const float* w3z = (const float*)d_in[9];

    bf16*  xb    = (bf16*)d_ws;                         // [512][4096]  bf16 (4 MB)
    bf16*  inter = xb + (size_t)T_DIM * H_DIM;          // [512][14336] bf16 (14.7 MB)
    float* parts = (float*)(inter + (size_t)T_DIM * F_DIM);

    const size_t base   = (size_t)T_DIM * H_DIM * 2 + (size_t)T_DIM * F_DIM * 2;
    const size_t pbytes = (size_t)T_DIM * H_DIM * 4;

    cvt_x_kernel<<<dim3(2048), dim3(256), 0, stream>>>(x, xb);

    gemm_gateup<<<dim3(F_DIM / 32), dim3(512), 0, stream>>>(
        xb, w1q, w1s, w1z, w3q, w3s, w3z, inter);

    if (ws_size >= base + 4 * pbytes) {
        gemm_down<4><<<dim3(H_DIM / 32, 4), dim3(512), 0, stream>>>(inter, w2q, w2s, w2z, parts);
        reduce_kernel<4><<<dim3(2048), dim3(256), 0, stream>>>(parts, (float*)d_out);
    } else if (ws_size >= base + 2 * pbytes) {
        gemm_down<2><<<dim3(H_DIM / 32, 2), dim3(512), 0, stream>>>(inter, w2q, w2s, w2z, parts);
        reduce_kernel<2><<<dim3(2048), dim3(256), 0, stream>>>(parts, (float*)d_out);
    } else {
        gemm_down<1><<<dim3(H_DIM / 32, 1), dim3(512), 0, stream>>>(inter, w2q, w2s, w2z, parts);
        reduce_kernel<1><<<dim3(2048), dim3(256), 0, stream>>>(parts, (float*)d_out);
    }
}